// Round 1
// baseline (239.550 us; speedup 1.0000x reference)
//
#include <hip/hip_runtime.h>
#include <hip/hip_bf16.h>

typedef __attribute__((ext_vector_type(8))) short bf16x8;
typedef __attribute__((ext_vector_type(4))) float f32x4;
typedef unsigned short u16;

#define MFMA16(a,b,c) __builtin_amdgcn_mfma_f32_16x16x32_bf16((a),(b),(c),0,0,0)

__device__ __forceinline__ u16 f2bf(float f) {
  union { float f; unsigned int u; } c; c.f = f;
  unsigned int u = c.u;
  return (u16)((u + 0x7FFFu + ((u >> 16) & 1u)) >> 16);
}

__device__ __forceinline__ void gl_lds16(const u16* g, u16* l) {
  __builtin_amdgcn_global_load_lds((const __attribute__((address_space(1))) void*)g,
                                   (__attribute__((address_space(3))) void*)l, 16, 0, 0);
}

// ---------------- X fp32 -> bf16 ----------------
__global__ __launch_bounds__(256) void convert_x(const float* __restrict__ X,
                                                 u16* __restrict__ Xb) {
  int i = (blockIdx.x * 256 + threadIdx.x) * 8;
  const float4* p = (const float4*)(X + i);
  float4 a = p[0], b = p[1];
  union { u16 h[8]; uint4 v; } o;
  o.h[0] = f2bf(a.x); o.h[1] = f2bf(a.y); o.h[2] = f2bf(a.z); o.h[3] = f2bf(a.w);
  o.h[4] = f2bf(b.x); o.h[5] = f2bf(b.y); o.h[6] = f2bf(b.z); o.h[7] = f2bf(b.w);
  *(uint4*)(Xb + i) = o.v;
}

// ---------------- W [k][n] fp32 -> WT [n][k] bf16 ----------------
__global__ __launch_bounds__(256) void transpose_w(const float* __restrict__ W,
                                                   u16* __restrict__ WT) {
  __shared__ float t[32][33];
  int n0 = blockIdx.x * 32, k0 = blockIdx.y * 32;
  int tx = threadIdx.x, ty = threadIdx.y; // 32 x 8
#pragma unroll
  for (int i = 0; i < 4; ++i)
    t[ty + i * 8][tx] = W[(size_t)(k0 + ty + i * 8) * 768 + n0 + tx];
  __syncthreads();
#pragma unroll
  for (int i = 0; i < 4; ++i)
    WT[(size_t)(n0 + ty + i * 8) * 768 + k0 + tx] = f2bf(t[tx][ty + i * 8]);
}

// ---------------- GEMM: C[m][n] = sum_k A[m][k] * BT[n][k] (+bias) ----------------
// MODE 0: QKV (N=2304): writes Q bf16 (scaled 1/8), K bf16, V bf16 TRANSPOSED per (b,h)
// MODE 1: out-proj (N=768): writes fp32 + bias
template <int MODE>
__global__ __launch_bounds__(256)
void gemm_bt(const u16* __restrict__ A, const u16* __restrict__ BT,
             const float* __restrict__ b0, const float* __restrict__ b1,
             const float* __restrict__ b2,
             u16* __restrict__ oQ, u16* __restrict__ oK, u16* __restrict__ oV,
             float* __restrict__ oF) {
  __shared__ __align__(16) u16 As[128 * 32];
  __shared__ __align__(16) u16 Bs[128 * 32];
  const int tid = threadIdx.x;
  const int wave = tid >> 6, lane = tid & 63, lg = lane >> 4, l15 = lane & 15;
  const int wr = wave >> 1, wc = wave & 1;
  const int M0 = blockIdx.x * 128, N0 = blockIdx.y * 128;
  const u16* Ap = A + (size_t)(M0 + (tid >> 2)) * 768 + (tid & 3) * 8;
  const u16* Bp = BT + (size_t)(N0 + (tid >> 2)) * 768 + (tid & 3) * 8;
  u16* Asd = As + tid * 8;
  u16* Bsd = Bs + tid * 8;
  f32x4 acc[4][4] = {};
  for (int kk = 0; kk < 768; kk += 32) {
    gl_lds16(Ap + kk, Asd);
    gl_lds16(Ap + kk + (size_t)64 * 768, Asd + 2048);
    gl_lds16(Bp + kk, Bsd);
    gl_lds16(Bp + kk + (size_t)64 * 768, Bsd + 2048);
    __syncthreads();
    bf16x8 af[4], bfr[4];
#pragma unroll
    for (int mt = 0; mt < 4; ++mt)
      af[mt] = *(const bf16x8*)(As + (wr * 64 + mt * 16 + l15) * 32 + lg * 8);
#pragma unroll
    for (int nt = 0; nt < 4; ++nt)
      bfr[nt] = *(const bf16x8*)(Bs + (wc * 64 + nt * 16 + l15) * 32 + lg * 8);
#pragma unroll
    for (int mt = 0; mt < 4; ++mt)
#pragma unroll
      for (int nt = 0; nt < 4; ++nt)
        acc[mt][nt] = MFMA16(af[mt], bfr[nt], acc[mt][nt]);
    __syncthreads();
  }
#pragma unroll
  for (int mt = 0; mt < 4; ++mt) {
    const int r0 = M0 + wr * 64 + mt * 16 + lg * 4;
#pragma unroll
    for (int nt = 0; nt < 4; ++nt) {
      const int ng = N0 + wc * 64 + nt * 16 + l15;
      f32x4 v = acc[mt][nt];
      if (MODE == 1) {
        const float bb = b0[ng];
#pragma unroll
        for (int r = 0; r < 4; ++r)
          oF[(size_t)(r0 + r) * 768 + ng] = v[r] + bb;
      } else {
        const int mat = ng / 768;
        const int col = ng - mat * 768;
        const float bb = (mat == 0 ? b0 : (mat == 1 ? b1 : b2))[col];
        if (mat == 0) {
#pragma unroll
          for (int r = 0; r < 4; ++r)
            oQ[(size_t)(r0 + r) * 768 + col] = f2bf((v[r] + bb) * 0.125f);
        } else if (mat == 1) {
#pragma unroll
          for (int r = 0; r < 4; ++r)
            oK[(size_t)(r0 + r) * 768 + col] = f2bf(v[r] + bb);
        } else {
          const int hh = col >> 6, dd = col & 63;
#pragma unroll
          for (int r = 0; r < 4; ++r) {
            const int rr = r0 + r;
            const int bbx = rr >> 9, ss = rr & 511;
            oV[((size_t)(bbx * 12 + hh) * 64 + dd) * 512 + ss] = f2bf(v[r] + bb);
          }
        }
      }
    }
  }
}

// ---------------- causal flash attention ----------------
// grid: (qt=8, h=12, b=32); 256 threads = 4 waves; wave handles 16 q-rows.
// Q: [16384][768] bf16 (pre-scaled). K: [16384][768] bf16. V: [b*12+h][64][512] bf16 (transposed).
// Out: [16384][768] bf16.
__global__ __launch_bounds__(256)
void flash(const u16* __restrict__ Q, const u16* __restrict__ K,
           const u16* __restrict__ V, u16* __restrict__ O) {
  __shared__ __align__(16) u16 Ks[4096]; // [2 d-half][64 key][32 d']
  __shared__ __align__(16) u16 Vs[4096]; // [2 k-half][64 d][32 key']
  __shared__ __align__(16) u16 Ps[4][1024]; // per wave [2 k-half][16 r][32 key']
  const int qt = blockIdx.x, h = blockIdx.y, b = blockIdx.z;
  const int tid = threadIdx.x, wave = tid >> 6, lane = tid & 63;
  const int lg = lane >> 4, l15 = lane & 15;
  bf16x8 qf[2];
  {
    const u16* qp = Q + (size_t)(b * 512 + qt * 64 + wave * 16 + l15) * 768 + h * 64 + lg * 8;
    qf[0] = *(const bf16x8*)qp;
    qf[1] = *(const bf16x8*)(qp + 32);
  }
  f32x4 oacc[4] = {};
  float m_run[4], l_run[4];
#pragma unroll
  for (int r = 0; r < 4; ++r) { m_run[r] = -1e30f; l_run[r] = 0.f; }
  const u16* Kg = K + (size_t)b * 512 * 768 + h * 64 + (size_t)(tid >> 2) * 768 + (tid & 3) * 8;
  const u16* Vg = V + (size_t)(b * 12 + h) * 64 * 512 + (size_t)(tid >> 2) * 512 + (tid & 3) * 8;
  u16* Ksd = Ks + tid * 8;
  u16* Vsd = Vs + tid * 8;
  u16* pw = Ps[wave];
  for (int kt = 0; kt <= qt; ++kt) {
    gl_lds16(Kg + (size_t)kt * 64 * 768, Ksd);
    gl_lds16(Kg + (size_t)kt * 64 * 768 + 32, Ksd + 2048);
    gl_lds16(Vg + kt * 64, Vsd);
    gl_lds16(Vg + kt * 64 + 32, Vsd + 2048);
    __syncthreads();
    // QK^T
    f32x4 sc[4] = {};
#pragma unroll
    for (int kc = 0; kc < 2; ++kc) {
#pragma unroll
      for (int t = 0; t < 4; ++t) {
        bf16x8 kf = *(const bf16x8*)(Ks + kc * 2048 + (t * 16 + l15) * 32 + lg * 8);
        sc[t] = MFMA16(qf[kc], kf, sc[t]);
      }
    }
    if (kt == qt) { // diagonal tile: causal mask
#pragma unroll
      for (int t = 0; t < 4; ++t)
#pragma unroll
        for (int r = 0; r < 4; ++r)
          if (t * 16 + l15 > wave * 16 + lg * 4 + r) sc[t][r] = -1e30f;
    }
    // online softmax (row groups of 16 lanes)
    float mx[4], fs[4], rs[4];
#pragma unroll
    for (int r = 0; r < 4; ++r) {
      float m = fmaxf(fmaxf(sc[0][r], sc[1][r]), fmaxf(sc[2][r], sc[3][r]));
      m = fmaxf(m, __shfl_xor(m, 1));
      m = fmaxf(m, __shfl_xor(m, 2));
      m = fmaxf(m, __shfl_xor(m, 4));
      m = fmaxf(m, __shfl_xor(m, 8));
      float mn = fmaxf(m_run[r], m);
      fs[r] = __expf(m_run[r] - mn);
      m_run[r] = mn;
      mx[r] = mn;
      rs[r] = 0.f;
    }
    u16 pb[4][4];
#pragma unroll
    for (int t = 0; t < 4; ++t)
#pragma unroll
      for (int r = 0; r < 4; ++r) {
        float p = __expf(sc[t][r] - mx[r]);
        rs[r] += p;
        pb[t][r] = f2bf(p);
      }
#pragma unroll
    for (int r = 0; r < 4; ++r) {
      rs[r] += __shfl_xor(rs[r], 1);
      rs[r] += __shfl_xor(rs[r], 2);
      rs[r] += __shfl_xor(rs[r], 4);
      rs[r] += __shfl_xor(rs[r], 8);
      l_run[r] = l_run[r] * fs[r] + rs[r];
    }
#pragma unroll
    for (int t = 0; t < 4; ++t)
#pragma unroll
      for (int r = 0; r < 4; ++r)
        oacc[t][r] *= fs[r];
    // stage P (per-wave LDS region)
#pragma unroll
    for (int t = 0; t < 4; ++t)
#pragma unroll
      for (int r = 0; r < 4; ++r)
        pw[(t >> 1) * 512 + (lg * 4 + r) * 32 + (t & 1) * 16 + l15] = pb[t][r];
    // PV
#pragma unroll
    for (int kc = 0; kc < 2; ++kc) {
      bf16x8 pf = *(const bf16x8*)(pw + kc * 512 + l15 * 32 + lg * 8);
#pragma unroll
      for (int t = 0; t < 4; ++t) {
        bf16x8 vf = *(const bf16x8*)(Vs + kc * 2048 + (t * 16 + l15) * 32 + lg * 8);
        oacc[t] = MFMA16(pf, vf, oacc[t]);
      }
    }
    __syncthreads();
  }
#pragma unroll
  for (int r = 0; r < 4; ++r) {
    float inv = 1.f / l_run[r];
#pragma unroll
    for (int t = 0; t < 4; ++t)
      O[(size_t)(b * 512 + qt * 64 + wave * 16 + lg * 4 + r) * 768 + h * 64 + t * 16 + l15] =
          f2bf(oacc[t][r] * inv);
  }
}

extern "C" void kernel_launch(void* const* d_in, const int* in_sizes, int n_in,
                              void* d_out, int out_size, void* d_ws, size_t ws_size,
                              hipStream_t stream) {
  (void)in_sizes; (void)n_in; (void)out_size; (void)ws_size;
  const float* X  = (const float*)d_in[0];
  // d_in[1] = causal mask: exactly triu(-1e9) -> equivalent to hard causal masking; unused.
  const float* Wq = (const float*)d_in[2];
  const float* bq = (const float*)d_in[3];
  const float* Wk = (const float*)d_in[4];
  const float* bk = (const float*)d_in[5];
  const float* Wv = (const float*)d_in[6];
  const float* bv = (const float*)d_in[7];
  const float* Wo = (const float*)d_in[8];
  const float* bo = (const float*)d_in[9];
  float* out = (float*)d_out;

  const size_t NME = (size_t)16384 * 768;
  u16* Xb  = (u16*)d_ws;        // bf16 X, later reused as attention output
  u16* Qs  = Xb + NME;
  u16* Kb  = Qs + NME;
  u16* Vt  = Kb + NME;          // [b*12+h][64][512]
  u16* WT  = Vt + NME;          // [2304][768]  (WqT | WkT | WvT)
  u16* WoT = WT + (size_t)2304 * 768;
  u16* Ao  = Xb;

  convert_x<<<6144, 256, 0, stream>>>(X, Xb);
  dim3 tb(32, 8);
  transpose_w<<<dim3(24, 24), tb, 0, stream>>>(Wq, WT);
  transpose_w<<<dim3(24, 24), tb, 0, stream>>>(Wk, WT + (size_t)768 * 768);
  transpose_w<<<dim3(24, 24), tb, 0, stream>>>(Wv, WT + (size_t)2 * 768 * 768);
  transpose_w<<<dim3(24, 24), tb, 0, stream>>>(Wo, WoT);
  gemm_bt<0><<<dim3(128, 18), 256, 0, stream>>>(Xb, WT, bq, bk, bv, Qs, Kb, Vt, nullptr);
  flash<<<dim3(8, 12, 32), 256, 0, stream>>>(Qs, Kb, Vt, Ao);
  gemm_bt<1><<<dim3(128, 6), 256, 0, stream>>>(Ao, WoT, bo, nullptr, nullptr,
                                               nullptr, nullptr, nullptr, out);
}